// Round 7
// baseline (335.361 us; speedup 1.0000x reference)
//
#include <hip/hip_runtime.h>

typedef __bf16 bf16_t;
typedef bf16_t bf16x8 __attribute__((ext_vector_type(8)));
typedef float f32x4 __attribute__((ext_vector_type(4)));

#define MFMA16(a, b, c) __builtin_amdgcn_mfma_f32_16x16x32_bf16(a, b, c, 0, 0, 0)

#define LOG2E 1.44269504f
#define C1 0.18033688f  // log2(e)/8 (SCALE = sqrt(64) = 8)

// s_waitcnt imm encodings (gfx9/CDNA): vmcnt[3:0] | expcnt<<4 | lgkmcnt<<8
#define WAIT_VM4_LGKM0 0x074  // vmcnt(4), lgkmcnt(0)
#define WAIT_VM2_LGKM0 0x072  // vmcnt(2), lgkmcnt(0)
#define WAIT_VM0_LGKM0 0x070  // vmcnt(0), lgkmcnt(0)

__device__ inline void barrier_ws() {
  __asm__ volatile("" ::: "memory");
  __builtin_amdgcn_s_barrier();
  __asm__ volatile("" ::: "memory");
}

__device__ inline void async_copy16(const bf16_t* g, bf16_t* l) {
  __builtin_amdgcn_global_load_lds(
      (const __attribute__((address_space(1))) void*)g,
      (__attribute__((address_space(3))) void*)l, 16, 0, 0);
}

// LDS tiles: 64-col rows of 8 chunks (16B); chunk c8 of row r lives at slot
// (c8 ^ (r & 7)) -> ds_read_b128 frag reads spread over all 32 banks.
__device__ inline bf16x8 lds_frag(const bf16_t* lds, int row, int c8) {
  return *(const bf16x8*)(lds + row * 64 + ((c8 ^ (row & 7)) << 3));
}

template <int NCHUNK, int NT>
__device__ inline void stage_tile(const bf16_t* __restrict__ g, size_t ld,
                                  bf16_t* lds, int tid) {
#pragma unroll
  for (int it = 0; it < NCHUNK / NT; ++it) {
    int f = it * NT + tid;
    int row = f >> 3;
    int c8 = (f & 7) ^ (row & 7);
    async_copy16(g + (size_t)row * ld + c8 * 8, lds + f * 8);
  }
}

// ------------- fp32 -> bf16 conversion + covout init + E table --------------
// E[b,h,k] = exp2(coverage[b,k] * Wcov[h] * log2e)  (bf16)
__global__ __launch_bounds__(256) void convert_kernel(
    const float* __restrict__ q, const float* __restrict__ mem,
    const float* __restrict__ wq, const float* __restrict__ wk,
    const float* __restrict__ wv, const float* __restrict__ wo,
    const float* __restrict__ coverage, const float* __restrict__ Wcov,
    bf16_t* Xq, bf16_t* Xm, bf16_t* Wqb, bf16_t* Wkb, bf16_t* Wvb,
    bf16_t* Wob, float* covout, bf16_t* covE) {
  size_t i = ((size_t)blockIdx.x * 256 + threadIdx.x) * 8;
  if (i >= 20979712u) {  // covE table
    size_t off = i - 20979712u;
    int k = (int)(off & 1023);
    int bh = (int)(off >> 10);
    int b = bh >> 4, h = bh & 15;
    float w = Wcov[h] * LOG2E;
    float4 c0 = *(const float4*)(coverage + (b << 10) + k);
    float4 c1 = *(const float4*)(coverage + (b << 10) + k + 4);
    union { bf16_t h8[8]; uint4 u; } t;
    t.h8[0] = (bf16_t)exp2f(c0.x * w); t.h8[1] = (bf16_t)exp2f(c0.y * w);
    t.h8[2] = (bf16_t)exp2f(c0.z * w); t.h8[3] = (bf16_t)exp2f(c0.w * w);
    t.h8[4] = (bf16_t)exp2f(c1.x * w); t.h8[5] = (bf16_t)exp2f(c1.y * w);
    t.h8[6] = (bf16_t)exp2f(c1.z * w); t.h8[7] = (bf16_t)exp2f(c1.w * w);
    *(uint4*)(covE + off) = t.u;
    return;
  }
  if (i >= 20971520u) {  // coverage -> covout init (f32 copy)
    size_t off = i - 20971520u;
    *(float4*)(covout + off) = *(const float4*)(coverage + off);
    *(float4*)(covout + off + 4) = *(const float4*)(coverage + off + 4);
    return;
  }
  const float* src;
  bf16_t* dst;
  size_t off;
  if (i < 8388608u)        { src = q;   dst = Xq;  off = i; }
  else if (i < 16777216u)  { src = mem; dst = Xm;  off = i - 8388608u; }
  else if (i < 17825792u)  { src = wq;  dst = Wqb; off = i - 16777216u; }
  else if (i < 18874368u)  { src = wk;  dst = Wkb; off = i - 17825792u; }
  else if (i < 19922944u)  { src = wv;  dst = Wvb; off = i - 18874368u; }
  else                     { src = wo;  dst = Wob; off = i - 19922944u; }
  float4 f0 = *(const float4*)(src + off);
  float4 f1 = *(const float4*)(src + off + 4);
  union { bf16_t h[8]; uint4 u; } t;
  t.h[0] = (bf16_t)f0.x; t.h[1] = (bf16_t)f0.y;
  t.h[2] = (bf16_t)f0.z; t.h[3] = (bf16_t)f0.w;
  t.h[4] = (bf16_t)f1.x; t.h[5] = (bf16_t)f1.y;
  t.h[6] = (bf16_t)f1.z; t.h[7] = (bf16_t)f1.w;
  *(uint4*)(dst + off) = t.u;
}

// ------------- fused QKV GEMM ------------------------------------------------
// Q-epilogue scales by C1 (folds softmax scale+log2e into Q).
// V-epilogue scales rows by E[b,h,k] (folds coverage bias out of attention).
__global__ __launch_bounds__(256) void gemm_qkv(
    const bf16_t* __restrict__ Xq, const bf16_t* __restrict__ Xm,
    const bf16_t* __restrict__ Wqkv, const float* __restrict__ bq,
    const float* __restrict__ bk, const float* __restrict__ bv,
    const bf16_t* __restrict__ covE, bf16_t* __restrict__ Qp,
    bf16_t* __restrict__ Kp, bf16_t* __restrict__ Vt) {
  __shared__ bf16_t As[128 * 64];
  __shared__ bf16_t Bs[128 * 64];
  const int tid = threadIdx.x;
  const int wave = tid >> 6, lane = tid & 63, quad = lane >> 4, c = lane & 15;
  const int wm = (wave & 1) * 64, wn = (wave >> 1) * 64;
  const size_t bm = blockIdx.x, bn = blockIdx.y;
  const int which = (int)(bn >> 3);  // 0=Q, 1=K, 2=V
  const bf16_t* A = which ? Xm : Xq;
  const float* bias = which == 0 ? bq : (which == 1 ? bk : bv);
  const bf16_t* Ab = A + bm * 128 * 1024;
  const bf16_t* Bb = Wqkv + bn * 128 * 1024;
  const f32x4 z4 = {0.f, 0.f, 0.f, 0.f};
  f32x4 acc[4][4];
#pragma unroll
  for (int i = 0; i < 4; ++i)
#pragma unroll
    for (int j = 0; j < 4; ++j) acc[i][j] = z4;

  for (int kt = 0; kt < 16; ++kt) {
    if (kt) __syncthreads();
    stage_tile<1024, 256>(Ab + kt * 64, 1024, As, tid);
    stage_tile<1024, 256>(Bb + kt * 64, 1024, Bs, tid);
    __syncthreads();
#pragma unroll
    for (int ks = 0; ks < 2; ++ks) {
      bf16x8 af[4], bfr[4];
#pragma unroll
      for (int i = 0; i < 4; ++i)
        af[i] = lds_frag(As, wm + 16 * i + c, ks * 4 + quad);
#pragma unroll
      for (int j = 0; j < 4; ++j)
        bfr[j] = lds_frag(Bs, wn + 16 * j + c, ks * 4 + quad);
#pragma unroll
      for (int i = 0; i < 4; ++i)
#pragma unroll
        for (int j = 0; j < 4; ++j)
          acc[i][j] = MFMA16(af[i], bfr[j], acc[i][j]);
    }
  }
#pragma unroll
  for (int i = 0; i < 4; ++i)
#pragma unroll
    for (int j = 0; j < 4; ++j) {
      int gc = (int)bn * 128 + wn + 16 * j + c;
      int gcl = gc & 1023;
      float bvv = bias[gcl];
      if (which == 2) {
        int b = (int)(bm >> 3);
        int hh = gcl >> 6;
        int kk = (int)(bm & 7) * 128 + wm + 16 * i + quad * 4;
        union { bf16_t h4[4]; uint2 u; } ev;
        ev.u = *(const uint2*)(covE + ((size_t)(b * 16 + hh)) * 1024 + kk);
        union { bf16_t h4[4]; uint2 u; } pk;
#pragma unroll
        for (int r = 0; r < 4; ++r)
          pk.h4[r] = (bf16_t)((acc[i][j][r] + bvv) * (float)ev.h4[r]);
        *(uint2*)(Vt + ((size_t)(b * 1024 + gcl)) * 1024 + kk) = pk.u;
      } else {
        bf16_t* Cout = which ? Kp : Qp;
        float scale = which ? 1.0f : C1;
        int gr0 = (int)bm * 128 + wm + 16 * i + quad * 4;
#pragma unroll
        for (int r = 0; r < 4; ++r)
          Cout[(size_t)(gr0 + r) * 1024 + gcl] =
              (bf16_t)((acc[i][j][r] + bvv) * scale);
      }
    }
}

// ------------- out-projection GEMM: out = Hb * Wo^T + bo (f32 out) ----------
__global__ __launch_bounds__(256) void gemm_out(
    const bf16_t* __restrict__ A, const bf16_t* __restrict__ Bw,
    const float* __restrict__ bias, float* __restrict__ Cout) {
  __shared__ bf16_t As[128 * 64];
  __shared__ bf16_t Bs[128 * 64];
  const int tid = threadIdx.x;
  const int wave = tid >> 6, lane = tid & 63, quad = lane >> 4, c = lane & 15;
  const int wm = (wave & 1) * 64, wn = (wave >> 1) * 64;
  const size_t bm = blockIdx.x, bn = blockIdx.y;
  const bf16_t* Ab = A + bm * 128 * 1024;
  const bf16_t* Bb = Bw + bn * 128 * 1024;
  const f32x4 z4 = {0.f, 0.f, 0.f, 0.f};
  f32x4 acc[4][4];
#pragma unroll
  for (int i = 0; i < 4; ++i)
#pragma unroll
    for (int j = 0; j < 4; ++j) acc[i][j] = z4;

  for (int kt = 0; kt < 16; ++kt) {
    if (kt) __syncthreads();
    stage_tile<1024, 256>(Ab + kt * 64, 1024, As, tid);
    stage_tile<1024, 256>(Bb + kt * 64, 1024, Bs, tid);
    __syncthreads();
#pragma unroll
    for (int ks = 0; ks < 2; ++ks) {
      bf16x8 af[4], bfr[4];
#pragma unroll
      for (int i = 0; i < 4; ++i)
        af[i] = lds_frag(As, wm + 16 * i + c, ks * 4 + quad);
#pragma unroll
      for (int j = 0; j < 4; ++j)
        bfr[j] = lds_frag(Bs, wn + 16 * j + c, ks * 4 + quad);
#pragma unroll
      for (int i = 0; i < 4; ++i)
#pragma unroll
        for (int j = 0; j < 4; ++j)
          acc[i][j] = MFMA16(af[i], bfr[j], acc[i][j]);
    }
  }
#pragma unroll
  for (int i = 0; i < 4; ++i)
#pragma unroll
    for (int j = 0; j < 4; ++j) {
      int gc = (int)bn * 128 + wn + 16 * j + c;
      float bvv = bias[gc];
      int gr0 = (int)bm * 128 + wm + 16 * i + quad * 4;
#pragma unroll
      for (int r = 0; r < 4; ++r)
        Cout[(size_t)(gr0 + r) * 1024 + gc] = acc[i][j][r] + bvv;
    }
}

// ------------- attention, single pass, high occupancy, XCD-local ------------
// 1D grid, 2048 blocks: id = (qt << 7) | (b << 4) | h. All 16 q-tiles of one
// (b,h) share id%8 -> same XCD -> K/V (256 KB/head) stay L2-resident
// (16 heads x 256 KB = 4 MB = one XCD L2).
__global__ __launch_bounds__(256, 6) void attn_fwd(
    const bf16_t* __restrict__ Qp, const bf16_t* __restrict__ Kp,
    const bf16_t* __restrict__ Vt, const bf16_t* __restrict__ covE,
    bf16_t* __restrict__ Hb, float* __restrict__ linvG) {
  __shared__ bf16_t QPs[64 * 64];  // Q staging, then per-wave P scratch
  __shared__ bf16_t Ks[64 * 64];
  __shared__ bf16_t Vs[64 * 64];
  __shared__ bf16_t Es[1024];
  const int tid = threadIdx.x;
  const int wave = tid >> 6, lane = tid & 63, quad = lane >> 4, c = lane & 15;
  const int id = blockIdx.x;
  const int bh = id & 127, q0 = (id >> 7) * 64;
  const int b = bh >> 4, h = bh & 15;
  const f32x4 z4 = {0.f, 0.f, 0.f, 0.f};
  const bf16_t* Kbase = Kp + ((size_t)b * 1024) * 1024 + h * 64;
  const bf16_t* Vbase = Vt + ((size_t)(b * 1024 + h * 64)) * 1024;

  // prologue staging: Q(2), E(1, half the threads), K0(2), V0(2)
  stage_tile<512, 256>(Qp + ((size_t)(b * 1024 + q0)) * 1024 + h * 64, 1024,
                       QPs, tid);
  if (tid < 128)
    async_copy16(covE + ((size_t)(b * 16 + h)) * 1024 + tid * 8,
                 Es + tid * 8);
  stage_tile<512, 256>(Kbase, 1024, Ks, tid);
  stage_tile<512, 256>(Vbase, 1024, Vs, tid);
  __builtin_amdgcn_s_waitcnt(WAIT_VM4_LGKM0);  // Q,E landed; K,V in flight
  barrier_ws();
  bf16x8 qf0 = lds_frag(QPs, wave * 16 + c, quad);
  bf16x8 qf1 = lds_frag(QPs, wave * 16 + c, 4 + quad);
  bf16_t* Pw = &QPs[wave * 16 * 64];  // overlays this wave's (now dead) Q rows

  f32x4 O[4] = {z4, z4, z4, z4};
  f32x4 Ol = z4;

  for (int kt = 0; kt < 16; ++kt) {
    if (kt) {
      __syncthreads();
      stage_tile<512, 256>(Kbase + (size_t)kt * 64 * 1024, 1024, Ks, tid);
      stage_tile<512, 256>(Vbase + kt * 64, 1024, Vs, tid);
    }
    __syncthreads();  // drains vmcnt -> K,V ready
    f32x4 S[4] = {z4, z4, z4, z4};
#pragma unroll
    for (int j = 0; j < 4; ++j) {
      S[j] = MFMA16(lds_frag(Ks, j * 16 + c, quad), qf0, S[j]);
      S[j] = MFMA16(lds_frag(Ks, j * 16 + c, 4 + quad), qf1, S[j]);
    }
#pragma unroll
    for (int j = 0; j < 4; ++j) {
      union { bf16_t h4[4]; uint2 u; } pk;
#pragma unroll
      for (int r = 0; r < 4; ++r) pk.h4[r] = (bf16_t)exp2f(S[j][r]);
      int k8 = j * 2 + (quad >> 1);
      *(uint2*)(Pw + c * 64 + ((k8 ^ (c & 7)) << 3) + (quad & 1) * 4) = pk.u;
    }
    // PV + l: same-wave LDS RAW (in-order pipe), no barrier needed
#pragma unroll
    for (int ks = 0; ks < 2; ++ks) {
      bf16x8 pb =
          *(const bf16x8*)(Pw + c * 64 + (((ks * 4 + quad) ^ (c & 7)) << 3));
      bf16x8 ef = *(const bf16x8*)(Es + kt * 64 + ks * 32 + quad * 8);
#pragma unroll
      for (int j = 0; j < 4; ++j)
        O[j] = MFMA16(lds_frag(Vs, j * 16 + c, ks * 4 + quad), pb, O[j]);
      Ol = MFMA16(ef, pb, Ol);
    }
  }

  float linv = 1.f / Ol[0];  // all acc rows equal l[q = q0 + wave*16 + c]
  if (quad == 0)
    linvG[((size_t)(b * 16 + h)) * 1024 + q0 + wave * 16 + c] = linv;

  size_t rowbase = ((size_t)(b * 1024 + q0 + wave * 16 + c)) * 1024 + h * 64;
#pragma unroll
  for (int j = 0; j < 4; ++j) {
    union { bf16_t h4[4]; uint2 u; } pk;
#pragma unroll
    for (int r = 0; r < 4; ++r) pk.h4[r] = (bf16_t)(O[j][r] * linv);
    *(uint2*)(Hb + rowbase + j * 16 + quad * 4) = pk.u;
  }
}

// ------------- coverage: recompute P colsums with stored 1/l ----------------
// 1D grid, XCD-local like attn: 16 k-tile blocks of one (b,h) share its Q
// stream + linv in L2. K register-resident; Q double-buffered raw-barrier
// pipeline. cs[j][r] += exp2(S)*linv[q]; E applied once at the end.
__global__ __launch_bounds__(256, 6) void cov_kernel(
    const bf16_t* __restrict__ Qp, const bf16_t* __restrict__ Kp,
    const bf16_t* __restrict__ covE, const float* __restrict__ linvG,
    float* __restrict__ covout) {
  __shared__ bf16_t Ks[64 * 64];
  __shared__ bf16_t Qs[2][64 * 64];
  __shared__ float covsum[64];
  const int tid = threadIdx.x;
  const int wave = tid >> 6, lane = tid & 63, quad = lane >> 4, c = lane & 15;
  const int id = blockIdx.x;
  const int bh = id & 127, k0 = (id >> 7) * 64;
  const int b = bh >> 4, h = bh & 15;
  const f32x4 z4 = {0.f, 0.f, 0.f, 0.f};
  const bf16_t* Qbase = Qp + ((size_t)b * 1024) * 1024 + h * 64;
  const float* lbase = linvG + ((size_t)(b * 16 + h)) * 1024 + wave * 16 + c;
  float lv_cur = lbase[0];

  if (tid < 64) covsum[tid] = 0.f;
  stage_tile<512, 256>(Kp + ((size_t)(b * 1024 + k0)) * 1024 + h * 64, 1024,
                       Ks, tid);
  stage_tile<512, 256>(Qbase, 1024, Qs[0], tid);

  float cs[4][4] = {};
  bf16x8 kf0[4], kf1[4];

  auto q_step = [&](int qt, const bf16_t* curQ, bf16_t* nxtQ) {
    float lv_nxt = 0.f;
    if (qt < 15) {
      lv_nxt = lbase[(qt + 1) * 64];
      stage_tile<512, 256>(Qbase + (size_t)(qt + 1) * 64 * 1024, 1024, nxtQ,
                           tid);
      __builtin_amdgcn_s_waitcnt(WAIT_VM2_LGKM0);
    } else {
      __builtin_amdgcn_s_waitcnt(WAIT_VM0_LGKM0);
    }
    barrier_ws();
    if (qt == 0) {
#pragma unroll
      for (int j = 0; j < 4; ++j) {
        kf0[j] = lds_frag(Ks, j * 16 + c, quad);
        kf1[j] = lds_frag(Ks, j * 16 + c, 4 + quad);
      }
    }
    bf16x8 qa = lds_frag(curQ, wave * 16 + c, quad);
    bf16x8 qb = lds_frag(curQ, wave * 16 + c, 4 + quad);
    f32x4 S[4] = {z4, z4, z4, z4};
#pragma unroll
    for (int j = 0; j < 4; ++j) {
      S[j] = MFMA16(kf0[j], qa, S[j]);
      S[j] = MFMA16(kf1[j], qb, S[j]);
    }
#pragma unroll
    for (int j = 0; j < 4; ++j)
#pragma unroll
      for (int r = 0; r < 4; ++r) cs[j][r] += exp2f(S[j][r]) * lv_cur;
    lv_cur = lv_nxt;
    barrier_ws();
  };

#pragma unroll 1
  for (int qt2 = 0; qt2 < 16; qt2 += 2) {
    q_step(qt2, Qs[0], Qs[1]);
    q_step(qt2 + 1, Qs[1], Qs[0]);
  }

#pragma unroll
  for (int j = 0; j < 4; ++j)
#pragma unroll
    for (int r = 0; r < 4; ++r) {
      float v = cs[j][r];
      v += __shfl_xor(v, 1);
      v += __shfl_xor(v, 2);
      v += __shfl_xor(v, 4);
      v += __shfl_xor(v, 8);
      if (c == 0) atomicAdd(&covsum[j * 16 + quad * 4 + r], v);
    }
  __syncthreads();
  if (tid < 64) {
    float e = (float)covE[((size_t)(b * 16 + h)) * 1024 + k0 + tid];
    atomicAdd(&covout[b * 1024 + k0 + tid], covsum[tid] * e * 0.0625f);
  }
}

extern "C" void kernel_launch(void* const* d_in, const int* in_sizes, int n_in,
                              void* d_out, int out_size, void* d_ws,
                              size_t ws_size, hipStream_t stream) {
  const float* query = (const float*)d_in[0];
  const float* memory = (const float*)d_in[1];
  const float* coverage = (const float*)d_in[2];
  const float* Wq = (const float*)d_in[3];
  const float* bq = (const float*)d_in[4];
  const float* Wk = (const float*)d_in[5];
  const float* bk = (const float*)d_in[6];
  const float* Wv = (const float*)d_in[7];
  const float* bv = (const float*)d_in[8];
  const float* Wo = (const float*)d_in[9];
  const float* bo = (const float*)d_in[10];
  const float* Wcov = (const float*)d_in[11];

  char* w = (char*)d_ws;
  const size_t MB = 1024 * 1024;
  bf16_t* Xq = (bf16_t*)(w + 0);
  bf16_t* Xm = (bf16_t*)(w + 16 * MB);
  bf16_t* Wqb = (bf16_t*)(w + 32 * MB);  // Wqb|Wkb|Wvb contiguous = Wqkv
  bf16_t* Wkb = (bf16_t*)(w + 34 * MB);
  bf16_t* Wvb = (bf16_t*)(w + 36 * MB);
  bf16_t* Wob = (bf16_t*)(w + 38 * MB);
  bf16_t* Qp = (bf16_t*)(w + 40 * MB);
  bf16_t* Kp = (bf16_t*)(w + 56 * MB);
  bf16_t* Vt = (bf16_t*)(w + 72 * MB);
  bf16_t* covE = (bf16_t*)(w + 88 * MB);  // 8*16*1024 bf16 = 256 KB
  bf16_t* Hb = (bf16_t*)(w + 0);          // reuses Xq (dead after QKV GEMM)
  float* linvG = (float*)(w + 16 * MB);   // reuses Xm (dead after QKV GEMM)

  float* out = (float*)d_out;
  float* covout = out + (size_t)8 * 1024 * 1024;

  convert_kernel<<<10308, 256, 0, stream>>>(query, memory, Wq, Wk, Wv, Wo,
                                            coverage, Wcov, Xq, Xm, Wqb, Wkb,
                                            Wvb, Wob, covout, covE);
  gemm_qkv<<<dim3(64, 24), 256, 0, stream>>>(Xq, Xm, Wqb, bq, bk, bv, covE,
                                             Qp, Kp, Vt);
  attn_fwd<<<2048, 256, 0, stream>>>(Qp, Kp, Vt, covE, Hb, linvG);
  cov_kernel<<<2048, 256, 0, stream>>>(Qp, Kp, covE, linvG, covout);
  gemm_out<<<dim3(64, 8), 256, 0, stream>>>(Hb, Wob, bo, out);
}

// Round 8
// 326.527 us; speedup vs baseline: 1.0271x; 1.0271x over previous
//
#include <hip/hip_runtime.h>

typedef __bf16 bf16_t;
typedef bf16_t bf16x8 __attribute__((ext_vector_type(8)));
typedef float f32x4 __attribute__((ext_vector_type(4)));

#define MFMA16(a, b, c) __builtin_amdgcn_mfma_f32_16x16x32_bf16(a, b, c, 0, 0, 0)

#define LOG2E 1.44269504f
#define C1 0.18033688f  // log2(e)/8 (SCALE = sqrt(64) = 8)
// raw v_exp_f32 — args are range-safe (|x| < ~8), no OCML fixup needed
#define EXP2(x) __builtin_amdgcn_exp2f(x)

// s_waitcnt imm encodings (gfx9/CDNA): vmcnt[3:0] | expcnt<<4 | lgkmcnt<<8
#define WAIT_VM4_LGKM0 0x074  // vmcnt(4), lgkmcnt(0)
#define WAIT_VM2_LGKM0 0x072  // vmcnt(2), lgkmcnt(0)
#define WAIT_VM0_LGKM0 0x070  // vmcnt(0), lgkmcnt(0)

__device__ inline void barrier_ws() {
  __asm__ volatile("" ::: "memory");
  __builtin_amdgcn_s_barrier();
  __asm__ volatile("" ::: "memory");
}

__device__ inline void async_copy16(const bf16_t* g, bf16_t* l) {
  __builtin_amdgcn_global_load_lds(
      (const __attribute__((address_space(1))) void*)g,
      (__attribute__((address_space(3))) void*)l, 16, 0, 0);
}

// LDS tiles: 64-col rows of 8 chunks (16B); chunk c8 of row r lives at slot
// (c8 ^ (r & 7)) -> ds_read_b128 frag reads spread over all 32 banks.
__device__ inline bf16x8 lds_frag(const bf16_t* lds, int row, int c8) {
  return *(const bf16x8*)(lds + row * 64 + ((c8 ^ (row & 7)) << 3));
}

template <int NCHUNK, int NT>
__device__ inline void stage_tile(const bf16_t* __restrict__ g, size_t ld,
                                  bf16_t* lds, int tid) {
#pragma unroll
  for (int it = 0; it < NCHUNK / NT; ++it) {
    int f = it * NT + tid;
    int row = f >> 3;
    int c8 = (f & 7) ^ (row & 7);
    async_copy16(g + (size_t)row * ld + c8 * 8, lds + f * 8);
  }
}

// ------------- fp32 -> bf16 conversion + covout init + E table --------------
// E[b,h,k] = exp2(coverage[b,k] * Wcov[h] * log2e)  (bf16)
__global__ __launch_bounds__(256) void convert_kernel(
    const float* __restrict__ q, const float* __restrict__ mem,
    const float* __restrict__ wq, const float* __restrict__ wk,
    const float* __restrict__ wv, const float* __restrict__ wo,
    const float* __restrict__ coverage, const float* __restrict__ Wcov,
    bf16_t* Xq, bf16_t* Xm, bf16_t* Wqb, bf16_t* Wkb, bf16_t* Wvb,
    bf16_t* Wob, float* covout, bf16_t* covE) {
  size_t i = ((size_t)blockIdx.x * 256 + threadIdx.x) * 8;
  if (i >= 20979712u) {  // covE table
    size_t off = i - 20979712u;
    int k = (int)(off & 1023);
    int bh = (int)(off >> 10);
    int b = bh >> 4, h = bh & 15;
    float w = Wcov[h] * LOG2E;
    float4 c0 = *(const float4*)(coverage + (b << 10) + k);
    float4 c1 = *(const float4*)(coverage + (b << 10) + k + 4);
    union { bf16_t h8[8]; uint4 u; } t;
    t.h8[0] = (bf16_t)EXP2(c0.x * w); t.h8[1] = (bf16_t)EXP2(c0.y * w);
    t.h8[2] = (bf16_t)EXP2(c0.z * w); t.h8[3] = (bf16_t)EXP2(c0.w * w);
    t.h8[4] = (bf16_t)EXP2(c1.x * w); t.h8[5] = (bf16_t)EXP2(c1.y * w);
    t.h8[6] = (bf16_t)EXP2(c1.z * w); t.h8[7] = (bf16_t)EXP2(c1.w * w);
    *(uint4*)(covE + off) = t.u;
    return;
  }
  if (i >= 20971520u) {  // coverage -> covout init (f32 copy)
    size_t off = i - 20971520u;
    *(float4*)(covout + off) = *(const float4*)(coverage + off);
    *(float4*)(covout + off + 4) = *(const float4*)(coverage + off + 4);
    return;
  }
  const float* src;
  bf16_t* dst;
  size_t off;
  if (i < 8388608u)        { src = q;   dst = Xq;  off = i; }
  else if (i < 16777216u)  { src = mem; dst = Xm;  off = i - 8388608u; }
  else if (i < 17825792u)  { src = wq;  dst = Wqb; off = i - 16777216u; }
  else if (i < 18874368u)  { src = wk;  dst = Wkb; off = i - 17825792u; }
  else if (i < 19922944u)  { src = wv;  dst = Wvb; off = i - 18874368u; }
  else                     { src = wo;  dst = Wob; off = i - 19922944u; }
  float4 f0 = *(const float4*)(src + off);
  float4 f1 = *(const float4*)(src + off + 4);
  union { bf16_t h[8]; uint4 u; } t;
  t.h[0] = (bf16_t)f0.x; t.h[1] = (bf16_t)f0.y;
  t.h[2] = (bf16_t)f0.z; t.h[3] = (bf16_t)f0.w;
  t.h[4] = (bf16_t)f1.x; t.h[5] = (bf16_t)f1.y;
  t.h[6] = (bf16_t)f1.z; t.h[7] = (bf16_t)f1.w;
  *(uint4*)(dst + off) = t.u;
}

// ------------- fused QKV GEMM ------------------------------------------------
// Q-epilogue scales by C1 (folds softmax scale+log2e into Q).
// V-epilogue scales rows by E[b,h,k] (folds coverage bias out of attention).
__global__ __launch_bounds__(256) void gemm_qkv(
    const bf16_t* __restrict__ Xq, const bf16_t* __restrict__ Xm,
    const bf16_t* __restrict__ Wqkv, const float* __restrict__ bq,
    const float* __restrict__ bk, const float* __restrict__ bv,
    const bf16_t* __restrict__ covE, bf16_t* __restrict__ Qp,
    bf16_t* __restrict__ Kp, bf16_t* __restrict__ Vt) {
  __shared__ bf16_t As[128 * 64];
  __shared__ bf16_t Bs[128 * 64];
  const int tid = threadIdx.x;
  const int wave = tid >> 6, lane = tid & 63, quad = lane >> 4, c = lane & 15;
  const int wm = (wave & 1) * 64, wn = (wave >> 1) * 64;
  const size_t bm = blockIdx.x, bn = blockIdx.y;
  const int which = (int)(bn >> 3);  // 0=Q, 1=K, 2=V
  const bf16_t* A = which ? Xm : Xq;
  const float* bias = which == 0 ? bq : (which == 1 ? bk : bv);
  const bf16_t* Ab = A + bm * 128 * 1024;
  const bf16_t* Bb = Wqkv + bn * 128 * 1024;
  const f32x4 z4 = {0.f, 0.f, 0.f, 0.f};
  f32x4 acc[4][4];
#pragma unroll
  for (int i = 0; i < 4; ++i)
#pragma unroll
    for (int j = 0; j < 4; ++j) acc[i][j] = z4;

  for (int kt = 0; kt < 16; ++kt) {
    if (kt) __syncthreads();
    stage_tile<1024, 256>(Ab + kt * 64, 1024, As, tid);
    stage_tile<1024, 256>(Bb + kt * 64, 1024, Bs, tid);
    __syncthreads();
#pragma unroll
    for (int ks = 0; ks < 2; ++ks) {
      bf16x8 af[4], bfr[4];
#pragma unroll
      for (int i = 0; i < 4; ++i)
        af[i] = lds_frag(As, wm + 16 * i + c, ks * 4 + quad);
#pragma unroll
      for (int j = 0; j < 4; ++j)
        bfr[j] = lds_frag(Bs, wn + 16 * j + c, ks * 4 + quad);
#pragma unroll
      for (int i = 0; i < 4; ++i)
#pragma unroll
        for (int j = 0; j < 4; ++j)
          acc[i][j] = MFMA16(af[i], bfr[j], acc[i][j]);
    }
  }
#pragma unroll
  for (int i = 0; i < 4; ++i)
#pragma unroll
    for (int j = 0; j < 4; ++j) {
      int gc = (int)bn * 128 + wn + 16 * j + c;
      int gcl = gc & 1023;
      float bvv = bias[gcl];
      if (which == 2) {
        int b = (int)(bm >> 3);
        int hh = gcl >> 6;
        int kk = (int)(bm & 7) * 128 + wm + 16 * i + quad * 4;
        union { bf16_t h4[4]; uint2 u; } ev;
        ev.u = *(const uint2*)(covE + ((size_t)(b * 16 + hh)) * 1024 + kk);
        union { bf16_t h4[4]; uint2 u; } pk;
#pragma unroll
        for (int r = 0; r < 4; ++r)
          pk.h4[r] = (bf16_t)((acc[i][j][r] + bvv) * (float)ev.h4[r]);
        *(uint2*)(Vt + ((size_t)(b * 1024 + gcl)) * 1024 + kk) = pk.u;
      } else {
        bf16_t* Cout = which ? Kp : Qp;
        float scale = which ? 1.0f : C1;
        int gr0 = (int)bm * 128 + wm + 16 * i + quad * 4;
#pragma unroll
        for (int r = 0; r < 4; ++r)
          Cout[(size_t)(gr0 + r) * 1024 + gcl] =
              (bf16_t)((acc[i][j][r] + bvv) * scale);
      }
    }
}

// ------------- out-projection GEMM: out = Hb * Wo^T + bo (f32 out) ----------
__global__ __launch_bounds__(256) void gemm_out(
    const bf16_t* __restrict__ A, const bf16_t* __restrict__ Bw,
    const float* __restrict__ bias, float* __restrict__ Cout) {
  __shared__ bf16_t As[128 * 64];
  __shared__ bf16_t Bs[128 * 64];
  const int tid = threadIdx.x;
  const int wave = tid >> 6, lane = tid & 63, quad = lane >> 4, c = lane & 15;
  const int wm = (wave & 1) * 64, wn = (wave >> 1) * 64;
  const size_t bm = blockIdx.x, bn = blockIdx.y;
  const bf16_t* Ab = A + bm * 128 * 1024;
  const bf16_t* Bb = Bw + bn * 128 * 1024;
  const f32x4 z4 = {0.f, 0.f, 0.f, 0.f};
  f32x4 acc[4][4];
#pragma unroll
  for (int i = 0; i < 4; ++i)
#pragma unroll
    for (int j = 0; j < 4; ++j) acc[i][j] = z4;

  for (int kt = 0; kt < 16; ++kt) {
    if (kt) __syncthreads();
    stage_tile<1024, 256>(Ab + kt * 64, 1024, As, tid);
    stage_tile<1024, 256>(Bb + kt * 64, 1024, Bs, tid);
    __syncthreads();
#pragma unroll
    for (int ks = 0; ks < 2; ++ks) {
      bf16x8 af[4], bfr[4];
#pragma unroll
      for (int i = 0; i < 4; ++i)
        af[i] = lds_frag(As, wm + 16 * i + c, ks * 4 + quad);
#pragma unroll
      for (int j = 0; j < 4; ++j)
        bfr[j] = lds_frag(Bs, wn + 16 * j + c, ks * 4 + quad);
#pragma unroll
      for (int i = 0; i < 4; ++i)
#pragma unroll
        for (int j = 0; j < 4; ++j)
          acc[i][j] = MFMA16(af[i], bfr[j], acc[i][j]);
    }
  }
#pragma unroll
  for (int i = 0; i < 4; ++i)
#pragma unroll
    for (int j = 0; j < 4; ++j) {
      int gc = (int)bn * 128 + wn + 16 * j + c;
      float bvv = bias[gc];
      int gr0 = (int)bm * 128 + wm + 16 * i + quad * 4;
#pragma unroll
      for (int r = 0; r < 4; ++r)
        Cout[(size_t)(gr0 + r) * 1024 + gc] = acc[i][j][r] + bvv;
    }
}

// ------------- attention, single pass, high occupancy, XCD-local ------------
// 1D grid, 2048 blocks: id = (qt << 7) | (b << 4) | h. All 16 q-tiles of one
// (b,h) share id%8 -> same XCD -> K/V (256 KB/head) stay L2-resident.
__global__ __launch_bounds__(256, 6) void attn_fwd(
    const bf16_t* __restrict__ Qp, const bf16_t* __restrict__ Kp,
    const bf16_t* __restrict__ Vt, const bf16_t* __restrict__ covE,
    bf16_t* __restrict__ Hb, float* __restrict__ linvG) {
  __shared__ bf16_t QPs[64 * 64];  // Q staging, then per-wave P scratch
  __shared__ bf16_t Ks[64 * 64];
  __shared__ bf16_t Vs[64 * 64];
  __shared__ bf16_t Es[1024];
  const int tid = threadIdx.x;
  const int wave = tid >> 6, lane = tid & 63, quad = lane >> 4, c = lane & 15;
  const int id = blockIdx.x;
  const int bh = id & 127, q0 = (id >> 7) * 64;
  const int b = bh >> 4, h = bh & 15;
  const f32x4 z4 = {0.f, 0.f, 0.f, 0.f};
  const bf16_t* Kbase = Kp + ((size_t)b * 1024) * 1024 + h * 64;
  const bf16_t* Vbase = Vt + ((size_t)(b * 1024 + h * 64)) * 1024;

  // prologue staging: Q(2), E(1, half the threads), K0(2), V0(2)
  stage_tile<512, 256>(Qp + ((size_t)(b * 1024 + q0)) * 1024 + h * 64, 1024,
                       QPs, tid);
  if (tid < 128)
    async_copy16(covE + ((size_t)(b * 16 + h)) * 1024 + tid * 8,
                 Es + tid * 8);
  stage_tile<512, 256>(Kbase, 1024, Ks, tid);
  stage_tile<512, 256>(Vbase, 1024, Vs, tid);
  __builtin_amdgcn_s_waitcnt(WAIT_VM4_LGKM0);  // Q,E landed; K,V in flight
  barrier_ws();
  bf16x8 qf0 = lds_frag(QPs, wave * 16 + c, quad);
  bf16x8 qf1 = lds_frag(QPs, wave * 16 + c, 4 + quad);
  bf16_t* Pw = &QPs[wave * 16 * 64];  // overlays this wave's (now dead) Q rows

  f32x4 O[4] = {z4, z4, z4, z4};
  f32x4 Ol = z4;

  for (int kt = 0; kt < 16; ++kt) {
    if (kt) {
      __syncthreads();
      stage_tile<512, 256>(Kbase + (size_t)kt * 64 * 1024, 1024, Ks, tid);
      stage_tile<512, 256>(Vbase + kt * 64, 1024, Vs, tid);
    }
    __syncthreads();  // drains vmcnt -> K,V ready
    f32x4 S[4] = {z4, z4, z4, z4};
#pragma unroll
    for (int j = 0; j < 4; ++j) {
      S[j] = MFMA16(lds_frag(Ks, j * 16 + c, quad), qf0, S[j]);
      S[j] = MFMA16(lds_frag(Ks, j * 16 + c, 4 + quad), qf1, S[j]);
    }
#pragma unroll
    for (int j = 0; j < 4; ++j) {
      union { bf16_t h4[4]; uint2 u; } pk;
#pragma unroll
      for (int r = 0; r < 4; ++r) pk.h4[r] = (bf16_t)EXP2(S[j][r]);
      int k8 = j * 2 + (quad >> 1);
      *(uint2*)(Pw + c * 64 + ((k8 ^ (c & 7)) << 3) + (quad & 1) * 4) = pk.u;
    }
    // PV + l: same-wave LDS RAW (in-order pipe), no barrier needed
#pragma unroll
    for (int ks = 0; ks < 2; ++ks) {
      bf16x8 pb =
          *(const bf16x8*)(Pw + c * 64 + (((ks * 4 + quad) ^ (c & 7)) << 3));
      bf16x8 ef = *(const bf16x8*)(Es + kt * 64 + ks * 32 + quad * 8);
#pragma unroll
      for (int j = 0; j < 4; ++j)
        O[j] = MFMA16(lds_frag(Vs, j * 16 + c, ks * 4 + quad), pb, O[j]);
      Ol = MFMA16(ef, pb, Ol);
    }
  }

  float linv = 1.f / Ol[0];  // all acc rows equal l[q = q0 + wave*16 + c]
  if (quad == 0)
    linvG[((size_t)(b * 16 + h)) * 1024 + q0 + wave * 16 + c] = linv;

  size_t rowbase = ((size_t)(b * 1024 + q0 + wave * 16 + c)) * 1024 + h * 64;
#pragma unroll
  for (int j = 0; j < 4; ++j) {
    union { bf16_t h4[4]; uint2 u; } pk;
#pragma unroll
    for (int r = 0; r < 4; ++r) pk.h4[r] = (bf16_t)(O[j][r] * linv);
    *(uint2*)(Hb + rowbase + j * 16 + quad * 4) = pk.u;
  }
}

// ------------- coverage: recompute P colsums with stored 1/l ----------------
// 1D grid, XCD-local like attn. K register-resident; Q double-buffered
// raw-barrier pipeline. cs[j][r] += exp2(S)*linv[q]; E applied at the end.
__global__ __launch_bounds__(256, 6) void cov_kernel(
    const bf16_t* __restrict__ Qp, const bf16_t* __restrict__ Kp,
    const bf16_t* __restrict__ covE, const float* __restrict__ linvG,
    float* __restrict__ covout) {
  __shared__ bf16_t Ks[64 * 64];
  __shared__ bf16_t Qs[2][64 * 64];
  __shared__ float covsum[64];
  const int tid = threadIdx.x;
  const int wave = tid >> 6, lane = tid & 63, quad = lane >> 4, c = lane & 15;
  const int id = blockIdx.x;
  const int bh = id & 127, k0 = (id >> 7) * 64;
  const int b = bh >> 4, h = bh & 15;
  const f32x4 z4 = {0.f, 0.f, 0.f, 0.f};
  const bf16_t* Qbase = Qp + ((size_t)b * 1024) * 1024 + h * 64;
  const float* lbase = linvG + ((size_t)(b * 16 + h)) * 1024 + wave * 16 + c;
  float lv_cur = lbase[0];

  if (tid < 64) covsum[tid] = 0.f;
  stage_tile<512, 256>(Kp + ((size_t)(b * 1024 + k0)) * 1024 + h * 64, 1024,
                       Ks, tid);
  stage_tile<512, 256>(Qbase, 1024, Qs[0], tid);

  float cs[4][4] = {};
  bf16x8 kf0[4], kf1[4];

  auto q_step = [&](int qt, const bf16_t* curQ, bf16_t* nxtQ) {
    float lv_nxt = 0.f;
    if (qt < 15) {
      lv_nxt = lbase[(qt + 1) * 64];
      stage_tile<512, 256>(Qbase + (size_t)(qt + 1) * 64 * 1024, 1024, nxtQ,
                           tid);
      __builtin_amdgcn_s_waitcnt(WAIT_VM2_LGKM0);
    } else {
      __builtin_amdgcn_s_waitcnt(WAIT_VM0_LGKM0);
    }
    barrier_ws();
    if (qt == 0) {
#pragma unroll
      for (int j = 0; j < 4; ++j) {
        kf0[j] = lds_frag(Ks, j * 16 + c, quad);
        kf1[j] = lds_frag(Ks, j * 16 + c, 4 + quad);
      }
    }
    bf16x8 qa = lds_frag(curQ, wave * 16 + c, quad);
    bf16x8 qb = lds_frag(curQ, wave * 16 + c, 4 + quad);
    f32x4 S[4] = {z4, z4, z4, z4};
#pragma unroll
    for (int j = 0; j < 4; ++j) {
      S[j] = MFMA16(kf0[j], qa, S[j]);
      S[j] = MFMA16(kf1[j], qb, S[j]);
    }
#pragma unroll
    for (int j = 0; j < 4; ++j)
#pragma unroll
      for (int r = 0; r < 4; ++r) cs[j][r] += EXP2(S[j][r]) * lv_cur;
    lv_cur = lv_nxt;
    barrier_ws();
  };

#pragma unroll 1
  for (int qt2 = 0; qt2 < 16; qt2 += 2) {
    q_step(qt2, Qs[0], Qs[1]);
    q_step(qt2 + 1, Qs[1], Qs[0]);
  }

#pragma unroll
  for (int j = 0; j < 4; ++j)
#pragma unroll
    for (int r = 0; r < 4; ++r) {
      float v = cs[j][r];
      v += __shfl_xor(v, 1);
      v += __shfl_xor(v, 2);
      v += __shfl_xor(v, 4);
      v += __shfl_xor(v, 8);
      if (c == 0) atomicAdd(&covsum[j * 16 + quad * 4 + r], v);
    }
  __syncthreads();
  if (tid < 64) {
    float e = (float)covE[((size_t)(b * 16 + h)) * 1024 + k0 + tid];
    atomicAdd(&covout[b * 1024 + k0 + tid], covsum[tid] * e * 0.0625f);
  }
}

extern "C" void kernel_launch(void* const* d_in, const int* in_sizes, int n_in,
                              void* d_out, int out_size, void* d_ws,
                              size_t ws_size, hipStream_t stream) {
  const float* query = (const float*)d_in[0];
  const float* memory = (const float*)d_in[1];
  const float* coverage = (const float*)d_in[2];
  const float* Wq = (const float*)d_in[3];
  const float* bq = (const float*)d_in[4];
  const float* Wk = (const float*)d_in[5];
  const float* bk = (const float*)d_in[6];
  const float* Wv = (const float*)d_in[7];
  const float* bv = (const float*)d_in[8];
  const float* Wo = (const float*)d_in[9];
  const float* bo = (const float*)d_in[10];
  const float* Wcov = (const float*)d_in[11];

  char* w = (char*)d_ws;
  const size_t MB = 1024 * 1024;
  bf16_t* Xq = (bf16_t*)(w + 0);
  bf16_t* Xm = (bf16_t*)(w + 16 * MB);
  bf16_t* Wqb = (bf16_t*)(w + 32 * MB);  // Wqb|Wkb|Wvb contiguous = Wqkv
  bf16_t* Wkb = (bf16_t*)(w + 34 * MB);
  bf16_t* Wvb = (bf16_t*)(w + 36 * MB);
  bf16_t* Wob = (bf16_t*)(w + 38 * MB);
  bf16_t* Qp = (bf16_t*)(w + 40 * MB);
  bf16_t* Kp = (bf16_t*)(w + 56 * MB);
  bf16_t* Vt = (bf16_t*)(w + 72 * MB);
  bf16_t* covE = (bf16_t*)(w + 88 * MB);  // 8*16*1024 bf16 = 256 KB
  bf16_t* Hb = (bf16_t*)(w + 0);          // reuses Xq (dead after QKV GEMM)
  float* linvG = (float*)(w + 16 * MB);   // reuses Xm (dead after QKV GEMM)

  float* out = (float*)d_out;
  float* covout = out + (size_t)8 * 1024 * 1024;

  convert_kernel<<<10308, 256, 0, stream>>>(query, memory, Wq, Wk, Wv, Wo,
                                            coverage, Wcov, Xq, Xm, Wqb, Wkb,
                                            Wvb, Wob, covout, covE);
  gemm_qkv<<<dim3(64, 24), 256, 0, stream>>>(Xq, Xm, Wqb, bq, bk, bv, covE,
                                             Qp, Kp, Vt);
  attn_fwd<<<2048, 256, 0, stream>>>(Qp, Kp, Vt, covE, Hb, linvG);
  cov_kernel<<<2048, 256, 0, stream>>>(Qp, Kp, covE, linvG, covout);
  gemm_out<<<dim3(64, 8), 256, 0, stream>>>(Hb, Wob, bo, out);
}

// Round 9
// 297.034 us; speedup vs baseline: 1.1290x; 1.0993x over previous
//
#include <hip/hip_runtime.h>

typedef __bf16 bf16_t;
typedef bf16_t bf16x8 __attribute__((ext_vector_type(8)));
typedef float f32x4 __attribute__((ext_vector_type(4)));

#define MFMA16(a, b, c) __builtin_amdgcn_mfma_f32_16x16x32_bf16(a, b, c, 0, 0, 0)

#define LOG2E 1.44269504f
#define C1 0.18033688f  // log2(e)/8 (SCALE = sqrt(64) = 8)
// raw v_exp_f32 — args are range-safe (|x| < ~8), no OCML fixup needed
#define EXP2(x) __builtin_amdgcn_exp2f(x)

// s_waitcnt imm encodings (gfx9/CDNA): vmcnt[3:0] | expcnt<<4 | lgkmcnt<<8
#define WAIT_VM4_LGKM0 0x074  // vmcnt(4), lgkmcnt(0)
#define WAIT_VM2_LGKM0 0x072  // vmcnt(2), lgkmcnt(0)
#define WAIT_VM0_LGKM0 0x070  // vmcnt(0), lgkmcnt(0)

__device__ inline void barrier_ws() {
  __asm__ volatile("" ::: "memory");
  __builtin_amdgcn_s_barrier();
  __asm__ volatile("" ::: "memory");
}

__device__ inline void async_copy16(const bf16_t* g, bf16_t* l) {
  __builtin_amdgcn_global_load_lds(
      (const __attribute__((address_space(1))) void*)g,
      (__attribute__((address_space(3))) void*)l, 16, 0, 0);
}

// LDS tiles: 64-col rows of 8 chunks (16B); chunk c8 of row r lives at slot
// (c8 ^ (r & 7)) -> ds_read_b128 frag reads spread over all 32 banks.
__device__ inline bf16x8 lds_frag(const bf16_t* lds, int row, int c8) {
  return *(const bf16x8*)(lds + row * 64 + ((c8 ^ (row & 7)) << 3));
}

template <int NCHUNK, int NT>
__device__ inline void stage_tile(const bf16_t* __restrict__ g, size_t ld,
                                  bf16_t* lds, int tid) {
#pragma unroll
  for (int it = 0; it < NCHUNK / NT; ++it) {
    int f = it * NT + tid;
    int row = f >> 3;
    int c8 = (f & 7) ^ (row & 7);
    async_copy16(g + (size_t)row * ld + c8 * 8, lds + f * 8);
  }
}

// ------------- fp32 -> bf16 conversion + covout init + E table --------------
// E[b,h,k] = exp2(coverage[b,k] * Wcov[h] * log2e)  (bf16)
__global__ __launch_bounds__(256) void convert_kernel(
    const float* __restrict__ q, const float* __restrict__ mem,
    const float* __restrict__ wq, const float* __restrict__ wk,
    const float* __restrict__ wv, const float* __restrict__ wo,
    const float* __restrict__ coverage, const float* __restrict__ Wcov,
    bf16_t* Xq, bf16_t* Xm, bf16_t* Wqb, bf16_t* Wkb, bf16_t* Wvb,
    bf16_t* Wob, float* covout, bf16_t* covE) {
  size_t i = ((size_t)blockIdx.x * 256 + threadIdx.x) * 8;
  if (i >= 20979712u) {  // covE table
    size_t off = i - 20979712u;
    int k = (int)(off & 1023);
    int bh = (int)(off >> 10);
    int b = bh >> 4, h = bh & 15;
    float w = Wcov[h] * LOG2E;
    float4 c0 = *(const float4*)(coverage + (b << 10) + k);
    float4 c1 = *(const float4*)(coverage + (b << 10) + k + 4);
    union { bf16_t h8[8]; uint4 u; } t;
    t.h8[0] = (bf16_t)EXP2(c0.x * w); t.h8[1] = (bf16_t)EXP2(c0.y * w);
    t.h8[2] = (bf16_t)EXP2(c0.z * w); t.h8[3] = (bf16_t)EXP2(c0.w * w);
    t.h8[4] = (bf16_t)EXP2(c1.x * w); t.h8[5] = (bf16_t)EXP2(c1.y * w);
    t.h8[6] = (bf16_t)EXP2(c1.z * w); t.h8[7] = (bf16_t)EXP2(c1.w * w);
    *(uint4*)(covE + off) = t.u;
    return;
  }
  if (i >= 20971520u) {  // coverage -> covout init (f32 copy)
    size_t off = i - 20971520u;
    *(float4*)(covout + off) = *(const float4*)(coverage + off);
    *(float4*)(covout + off + 4) = *(const float4*)(coverage + off + 4);
    return;
  }
  const float* src;
  bf16_t* dst;
  size_t off;
  if (i < 8388608u)        { src = q;   dst = Xq;  off = i; }
  else if (i < 16777216u)  { src = mem; dst = Xm;  off = i - 8388608u; }
  else if (i < 17825792u)  { src = wq;  dst = Wqb; off = i - 16777216u; }
  else if (i < 18874368u)  { src = wk;  dst = Wkb; off = i - 17825792u; }
  else if (i < 19922944u)  { src = wv;  dst = Wvb; off = i - 18874368u; }
  else                     { src = wo;  dst = Wob; off = i - 19922944u; }
  float4 f0 = *(const float4*)(src + off);
  float4 f1 = *(const float4*)(src + off + 4);
  union { bf16_t h[8]; uint4 u; } t;
  t.h[0] = (bf16_t)f0.x; t.h[1] = (bf16_t)f0.y;
  t.h[2] = (bf16_t)f0.z; t.h[3] = (bf16_t)f0.w;
  t.h[4] = (bf16_t)f1.x; t.h[5] = (bf16_t)f1.y;
  t.h[6] = (bf16_t)f1.z; t.h[7] = (bf16_t)f1.w;
  *(uint4*)(dst + off) = t.u;
}

// ------------- fused QKV GEMM ------------------------------------------------
// Q-epilogue scales by C1 (folds softmax scale+log2e into Q).
// V-epilogue scales rows by E[b,h,k] (folds coverage bias out of attention).
__global__ __launch_bounds__(256) void gemm_qkv(
    const bf16_t* __restrict__ Xq, const bf16_t* __restrict__ Xm,
    const bf16_t* __restrict__ Wqkv, const float* __restrict__ bq,
    const float* __restrict__ bk, const float* __restrict__ bv,
    const bf16_t* __restrict__ covE, bf16_t* __restrict__ Qp,
    bf16_t* __restrict__ Kp, bf16_t* __restrict__ Vt) {
  __shared__ bf16_t As[128 * 64];
  __shared__ bf16_t Bs[128 * 64];
  const int tid = threadIdx.x;
  const int wave = tid >> 6, lane = tid & 63, quad = lane >> 4, c = lane & 15;
  const int wm = (wave & 1) * 64, wn = (wave >> 1) * 64;
  const size_t bm = blockIdx.x, bn = blockIdx.y;
  const int which = (int)(bn >> 3);  // 0=Q, 1=K, 2=V
  const bf16_t* A = which ? Xm : Xq;
  const float* bias = which == 0 ? bq : (which == 1 ? bk : bv);
  const bf16_t* Ab = A + bm * 128 * 1024;
  const bf16_t* Bb = Wqkv + bn * 128 * 1024;
  const f32x4 z4 = {0.f, 0.f, 0.f, 0.f};
  f32x4 acc[4][4];
#pragma unroll
  for (int i = 0; i < 4; ++i)
#pragma unroll
    for (int j = 0; j < 4; ++j) acc[i][j] = z4;

  for (int kt = 0; kt < 16; ++kt) {
    if (kt) __syncthreads();
    stage_tile<1024, 256>(Ab + kt * 64, 1024, As, tid);
    stage_tile<1024, 256>(Bb + kt * 64, 1024, Bs, tid);
    __syncthreads();
#pragma unroll
    for (int ks = 0; ks < 2; ++ks) {
      bf16x8 af[4], bfr[4];
#pragma unroll
      for (int i = 0; i < 4; ++i)
        af[i] = lds_frag(As, wm + 16 * i + c, ks * 4 + quad);
#pragma unroll
      for (int j = 0; j < 4; ++j)
        bfr[j] = lds_frag(Bs, wn + 16 * j + c, ks * 4 + quad);
#pragma unroll
      for (int i = 0; i < 4; ++i)
#pragma unroll
        for (int j = 0; j < 4; ++j)
          acc[i][j] = MFMA16(af[i], bfr[j], acc[i][j]);
    }
  }
#pragma unroll
  for (int i = 0; i < 4; ++i)
#pragma unroll
    for (int j = 0; j < 4; ++j) {
      int gc = (int)bn * 128 + wn + 16 * j + c;
      int gcl = gc & 1023;
      float bvv = bias[gcl];
      if (which == 2) {
        int b = (int)(bm >> 3);
        int hh = gcl >> 6;
        int kk = (int)(bm & 7) * 128 + wm + 16 * i + quad * 4;
        union { bf16_t h4[4]; uint2 u; } ev;
        ev.u = *(const uint2*)(covE + ((size_t)(b * 16 + hh)) * 1024 + kk);
        union { bf16_t h4[4]; uint2 u; } pk;
#pragma unroll
        for (int r = 0; r < 4; ++r)
          pk.h4[r] = (bf16_t)((acc[i][j][r] + bvv) * (float)ev.h4[r]);
        *(uint2*)(Vt + ((size_t)(b * 1024 + gcl)) * 1024 + kk) = pk.u;
      } else {
        bf16_t* Cout = which ? Kp : Qp;
        float scale = which ? 1.0f : C1;
        int gr0 = (int)bm * 128 + wm + 16 * i + quad * 4;
#pragma unroll
        for (int r = 0; r < 4; ++r)
          Cout[(size_t)(gr0 + r) * 1024 + gcl] =
              (bf16_t)((acc[i][j][r] + bvv) * scale);
      }
    }
}

// ------------- attention: 512 thr, 128 q/block, full occupancy, XCD-local ---
// 1024 blocks = exactly 4/CU x 8 waves = 32 waves/CU. id low 7 bits = (b,h)
// -> all 8 q-tiles of a head on one XCD (K/V L2-resident). Q staging buffer
// becomes per-wave P scratch after q-frags are register-resident.
__global__ __launch_bounds__(512, 8) void attn_fwd(
    const bf16_t* __restrict__ Qp, const bf16_t* __restrict__ Kp,
    const bf16_t* __restrict__ Vt, const bf16_t* __restrict__ covE,
    bf16_t* __restrict__ Hb, float* __restrict__ linvG) {
  __shared__ bf16_t QPs[128 * 64];  // Q staging, then per-wave P scratch
  __shared__ bf16_t Ks[64 * 64];
  __shared__ bf16_t Vs[64 * 64];
  __shared__ bf16_t Es[1024];
  const int tid = threadIdx.x;
  const int wave = tid >> 6, lane = tid & 63, quad = lane >> 4, c = lane & 15;
  const int id = blockIdx.x;
  const int bh = id & 127, q0 = (id >> 7) * 128;
  const int b = bh >> 4, h = bh & 15;
  const f32x4 z4 = {0.f, 0.f, 0.f, 0.f};
  const bf16_t* Kbase = Kp + ((size_t)b * 1024) * 1024 + h * 64;
  const bf16_t* Vbase = Vt + ((size_t)(b * 1024 + h * 64)) * 1024;

  // prologue staging: Q(2 loads/thread), E(1, tid<128), K0(1), V0(1)
  stage_tile<1024, 512>(Qp + ((size_t)(b * 1024 + q0)) * 1024 + h * 64, 1024,
                        QPs, tid);
  if (tid < 128)
    async_copy16(covE + ((size_t)(b * 16 + h)) * 1024 + tid * 8,
                 Es + tid * 8);
  stage_tile<512, 512>(Kbase, 1024, Ks, tid);
  stage_tile<512, 512>(Vbase, 1024, Vs, tid);
  __builtin_amdgcn_s_waitcnt(WAIT_VM2_LGKM0);  // Q,E landed; K,V in flight
  barrier_ws();
  bf16x8 qf0 = lds_frag(QPs, wave * 16 + c, quad);
  bf16x8 qf1 = lds_frag(QPs, wave * 16 + c, 4 + quad);
  bf16_t* Pw = &QPs[wave * 16 * 64];  // overlays this wave's (now dead) Q rows

  f32x4 O[4] = {z4, z4, z4, z4};
  f32x4 Ol = z4;

  for (int kt = 0; kt < 16; ++kt) {
    if (kt) {
      __syncthreads();
      stage_tile<512, 512>(Kbase + (size_t)kt * 64 * 1024, 1024, Ks, tid);
      stage_tile<512, 512>(Vbase + kt * 64, 1024, Vs, tid);
    }
    __syncthreads();  // drains vmcnt -> K,V ready
    f32x4 S[4] = {z4, z4, z4, z4};
#pragma unroll
    for (int j = 0; j < 4; ++j) {
      S[j] = MFMA16(lds_frag(Ks, j * 16 + c, quad), qf0, S[j]);
      S[j] = MFMA16(lds_frag(Ks, j * 16 + c, 4 + quad), qf1, S[j]);
    }
#pragma unroll
    for (int j = 0; j < 4; ++j) {
      union { bf16_t h4[4]; uint2 u; } pk;
#pragma unroll
      for (int r = 0; r < 4; ++r) pk.h4[r] = (bf16_t)EXP2(S[j][r]);
      int k8 = j * 2 + (quad >> 1);
      *(uint2*)(Pw + c * 64 + ((k8 ^ (c & 7)) << 3) + (quad & 1) * 4) = pk.u;
    }
    // PV + l: same-wave LDS RAW (in-order pipe), no barrier needed
#pragma unroll
    for (int ks = 0; ks < 2; ++ks) {
      bf16x8 pb =
          *(const bf16x8*)(Pw + c * 64 + (((ks * 4 + quad) ^ (c & 7)) << 3));
      bf16x8 ef = *(const bf16x8*)(Es + kt * 64 + ks * 32 + quad * 8);
#pragma unroll
      for (int j = 0; j < 4; ++j)
        O[j] = MFMA16(lds_frag(Vs, j * 16 + c, ks * 4 + quad), pb, O[j]);
      Ol = MFMA16(ef, pb, Ol);
    }
  }

  float linv = 1.f / Ol[0];  // all acc rows equal l[q = q0 + wave*16 + c]
  if (quad == 0)
    linvG[((size_t)(b * 16 + h)) * 1024 + q0 + wave * 16 + c] = linv;

  size_t rowbase = ((size_t)(b * 1024 + q0 + wave * 16 + c)) * 1024 + h * 64;
#pragma unroll
  for (int j = 0; j < 4; ++j) {
    union { bf16_t h4[4]; uint2 u; } pk;
#pragma unroll
    for (int r = 0; r < 4; ++r) pk.h4[r] = (bf16_t)(O[j][r] * linv);
    *(uint2*)(Hb + rowbase + j * 16 + quad * 4) = pk.u;
  }
}

// ------------- merged tail: coverage colsums (blocks 0..2047) ---------------
// ------------- + out-projection GEMM (blocks 2048..2559) --------------------
__device__ __forceinline__ void cov_path(
    char* smem, int id, const bf16_t* __restrict__ Qp,
    const bf16_t* __restrict__ Kp, const bf16_t* __restrict__ covE,
    const float* __restrict__ linvG, float* __restrict__ covout) {
  bf16_t* Ks = (bf16_t*)smem;              // 8 KB
  bf16_t* Qs0 = (bf16_t*)(smem + 8192);    // 8 KB
  bf16_t* Qs1 = (bf16_t*)(smem + 16384);   // 8 KB
  float* covsum = (float*)(smem + 24576);  // 256 B
  const int tid = threadIdx.x;
  const int wave = tid >> 6, lane = tid & 63, quad = lane >> 4, c = lane & 15;
  const int bh = id & 127, k0 = (id >> 7) * 64;
  const int b = bh >> 4, h = bh & 15;
  const f32x4 z4 = {0.f, 0.f, 0.f, 0.f};
  const bf16_t* Qbase = Qp + ((size_t)b * 1024) * 1024 + h * 64;
  const float* lbase = linvG + ((size_t)(b * 16 + h)) * 1024 + wave * 16 + c;
  float lv_cur = lbase[0];

  if (tid < 64) covsum[tid] = 0.f;
  stage_tile<512, 256>(Kp + ((size_t)(b * 1024 + k0)) * 1024 + h * 64, 1024,
                       Ks, tid);
  stage_tile<512, 256>(Qbase, 1024, Qs0, tid);

  float cs[4][4] = {};
  bf16x8 kf0[4], kf1[4];

  auto q_step = [&](int qt, const bf16_t* curQ, bf16_t* nxtQ) {
    float lv_nxt = 0.f;
    if (qt < 15) {
      lv_nxt = lbase[(qt + 1) * 64];
      stage_tile<512, 256>(Qbase + (size_t)(qt + 1) * 64 * 1024, 1024, nxtQ,
                           tid);
      __builtin_amdgcn_s_waitcnt(WAIT_VM2_LGKM0);
    } else {
      __builtin_amdgcn_s_waitcnt(WAIT_VM0_LGKM0);
    }
    barrier_ws();
    if (qt == 0) {
#pragma unroll
      for (int j = 0; j < 4; ++j) {
        kf0[j] = lds_frag(Ks, j * 16 + c, quad);
        kf1[j] = lds_frag(Ks, j * 16 + c, 4 + quad);
      }
    }
    bf16x8 qa = lds_frag(curQ, wave * 16 + c, quad);
    bf16x8 qb = lds_frag(curQ, wave * 16 + c, 4 + quad);
    f32x4 S[4] = {z4, z4, z4, z4};
#pragma unroll
    for (int j = 0; j < 4; ++j) {
      S[j] = MFMA16(kf0[j], qa, S[j]);
      S[j] = MFMA16(kf1[j], qb, S[j]);
    }
#pragma unroll
    for (int j = 0; j < 4; ++j)
#pragma unroll
      for (int r = 0; r < 4; ++r) cs[j][r] += EXP2(S[j][r]) * lv_cur;
    lv_cur = lv_nxt;
    barrier_ws();
  };

#pragma unroll 1
  for (int qt2 = 0; qt2 < 16; qt2 += 2) {
    q_step(qt2, Qs0, Qs1);
    q_step(qt2 + 1, Qs1, Qs0);
  }

#pragma unroll
  for (int j = 0; j < 4; ++j)
#pragma unroll
    for (int r = 0; r < 4; ++r) {
      float v = cs[j][r];
      v += __shfl_xor(v, 1);
      v += __shfl_xor(v, 2);
      v += __shfl_xor(v, 4);
      v += __shfl_xor(v, 8);
      if (c == 0) atomicAdd(&covsum[j * 16 + quad * 4 + r], v);
    }
  __syncthreads();
  if (tid < 64) {
    float e = (float)covE[((size_t)(b * 16 + h)) * 1024 + k0 + tid];
    atomicAdd(&covout[b * 1024 + k0 + tid], covsum[tid] * e * 0.0625f);
  }
}

__device__ __forceinline__ void gemm_out_path(
    char* smem, int id2, const bf16_t* __restrict__ A,
    const bf16_t* __restrict__ Bw, const float* __restrict__ bias,
    float* __restrict__ Cout) {
  bf16_t* As = (bf16_t*)smem;            // 16 KB
  bf16_t* Bs = (bf16_t*)(smem + 16384);  // 16 KB
  const int tid = threadIdx.x;
  const int wave = tid >> 6, lane = tid & 63, quad = lane >> 4, c = lane & 15;
  const int wm = (wave & 1) * 64, wn = (wave >> 1) * 64;
  const size_t bm = id2 & 63, bn = id2 >> 6;
  const bf16_t* Ab = A + bm * 128 * 1024;
  const bf16_t* Bb = Bw + bn * 128 * 1024;
  const f32x4 z4 = {0.f, 0.f, 0.f, 0.f};
  f32x4 acc[4][4];
#pragma unroll
  for (int i = 0; i < 4; ++i)
#pragma unroll
    for (int j = 0; j < 4; ++j) acc[i][j] = z4;

  for (int kt = 0; kt < 16; ++kt) {
    if (kt) __syncthreads();
    stage_tile<1024, 256>(Ab + kt * 64, 1024, As, tid);
    stage_tile<1024, 256>(Bb + kt * 64, 1024, Bs, tid);
    __syncthreads();
#pragma unroll
    for (int ks = 0; ks < 2; ++ks) {
      bf16x8 af[4], bfr[4];
#pragma unroll
      for (int i = 0; i < 4; ++i)
        af[i] = lds_frag(As, wm + 16 * i + c, ks * 4 + quad);
#pragma unroll
      for (int j = 0; j < 4; ++j)
        bfr[j] = lds_frag(Bs, wn + 16 * j + c, ks * 4 + quad);
#pragma unroll
      for (int i = 0; i < 4; ++i)
#pragma unroll
        for (int j = 0; j < 4; ++j)
          acc[i][j] = MFMA16(af[i], bfr[j], acc[i][j]);
    }
  }
#pragma unroll
  for (int i = 0; i < 4; ++i)
#pragma unroll
    for (int j = 0; j < 4; ++j) {
      int gc = (int)bn * 128 + wn + 16 * j + c;
      float bvv = bias[gc];
      int gr0 = (int)bm * 128 + wm + 16 * i + quad * 4;
#pragma unroll
      for (int r = 0; r < 4; ++r)
        Cout[(size_t)(gr0 + r) * 1024 + gc] = acc[i][j][r] + bvv;
    }
}

__global__ __launch_bounds__(256) void tail_kernel(
    const bf16_t* __restrict__ Qp, const bf16_t* __restrict__ Kp,
    const bf16_t* __restrict__ covE, const float* __restrict__ linvG,
    float* __restrict__ covout, const bf16_t* __restrict__ Hb,
    const bf16_t* __restrict__ Wob, const float* __restrict__ bo,
    float* __restrict__ out) {
  __shared__ __align__(16) char smem[33024];
  if (blockIdx.x < 2048)
    cov_path(smem, blockIdx.x, Qp, Kp, covE, linvG, covout);
  else
    gemm_out_path(smem, blockIdx.x - 2048, Hb, Wob, bo, out);
}

extern "C" void kernel_launch(void* const* d_in, const int* in_sizes, int n_in,
                              void* d_out, int out_size, void* d_ws,
                              size_t ws_size, hipStream_t stream) {
  const float* query = (const float*)d_in[0];
  const float* memory = (const float*)d_in[1];
  const float* coverage = (const float*)d_in[2];
  const float* Wq = (const float*)d_in[3];
  const float* bq = (const float*)d_in[4];
  const float* Wk = (const float*)d_in[5];
  const float* bk = (const float*)d_in[6];
  const float* Wv = (const float*)d_in[7];
  const float* bv = (const float*)d_in[8];
  const float* Wo = (const float*)d_in[9];
  const float* bo = (const float*)d_in[10];
  const float* Wcov = (const float*)d_in[11];

  char* w = (char*)d_ws;
  const size_t MB = 1024 * 1024;
  bf16_t* Xq = (bf16_t*)(w + 0);
  bf16_t* Xm = (bf16_t*)(w + 16 * MB);
  bf16_t* Wqb = (bf16_t*)(w + 32 * MB);  // Wqb|Wkb|Wvb contiguous = Wqkv
  bf16_t* Wkb = (bf16_t*)(w + 34 * MB);
  bf16_t* Wvb = (bf16_t*)(w + 36 * MB);
  bf16_t* Wob = (bf16_t*)(w + 38 * MB);
  bf16_t* Qp = (bf16_t*)(w + 40 * MB);
  bf16_t* Kp = (bf16_t*)(w + 56 * MB);
  bf16_t* Vt = (bf16_t*)(w + 72 * MB);
  bf16_t* covE = (bf16_t*)(w + 88 * MB);  // 8*16*1024 bf16 = 256 KB
  bf16_t* Hb = (bf16_t*)(w + 0);          // reuses Xq (dead after QKV GEMM)
  float* linvG = (float*)(w + 16 * MB);   // reuses Xm (dead after QKV GEMM)

  float* out = (float*)d_out;
  float* covout = out + (size_t)8 * 1024 * 1024;

  convert_kernel<<<10308, 256, 0, stream>>>(query, memory, Wq, Wk, Wv, Wo,
                                            coverage, Wcov, Xq, Xm, Wqb, Wkb,
                                            Wvb, Wob, covout, covE);
  gemm_qkv<<<dim3(64, 24), 256, 0, stream>>>(Xq, Xm, Wqb, bq, bk, bv, covE,
                                             Qp, Kp, Vt);
  attn_fwd<<<1024, 512, 0, stream>>>(Qp, Kp, Vt, covE, Hb, linvG);
  tail_kernel<<<2560, 256, 0, stream>>>(Qp, Kp, covE, linvG, covout, Hb, Wob,
                                        bo, out);
}